// Round 4
// baseline (1033.249 us; speedup 1.0000x reference)
//
#include <hip/hip_runtime.h>
#include <math.h>
#include <float.h>

#define H 1080
#define W 1920
#define HWSZ (H*W)
#define NPART 25
#define NCH 26          // heatmap channels in memory (NPART+1)
#define NLIMB 26
#define KTOP 32
#define MID 10
#define RAD 12

// Tile geometry for fused blur+peak kernel
#define TH 32
#define TW 64
#define LRP 62               // input rows: y0-13 .. y0+44  (covers +/-13 recheck window)
#define LC  90               // input cols: x0-13 .. x0+76
#define VRR 34               // vertical-blur rows (y0-1 .. y0+32)
#define VCS 93               // v col stride (93%32=29, coprime -> bank spread)
#define SR  34               // sm rows
#define SC  66               // sm cols (real)
#define SCS 67               // smv col stride (67%32=3, coprime -> bank spread)

#define EPS 1e-5f            // screen margin; hard f32-vs-f64 bound ~3.8e-6 -> 2.6x headroom

// Output layout (floats): px[25*32] py[25*32] score[25*32] mask[25*32] conn[26*32*32]
#define OFF_PY   800
#define OFF_SC   1600
#define OFF_MK   2400
#define OFF_CONN 3200

__device__ __constant__ int LIMBS_d[NLIMB * 2] = {
    1,8, 1,2, 1,5, 2,3, 3,4, 5,6, 6,7, 8,9, 9,10, 10,11, 8,12, 12,13, 13,14,
    1,0, 0,15, 15,16, 0,17, 0,18, 14,19, 19,20, 14,21, 11,22, 22,23, 11,24, 2,17, 5,18
};

__device__ __forceinline__ int symH(int y) {
    if (y < 0) return -1 - y;
    if (y >= H) return 2 * H - 1 - y;
    return y;
}
__device__ __forceinline__ int symW(int x) {
    if (x < 0) return -1 - x;
    if (x >= W) return 2 * W - 1 - x;
    return x;
}

// ---------------------------------------------------------------------------
// Kernel T: channels-last (H,W,26) -> 25 planar (H,W) f32 images (bit-exact copy)
// ---------------------------------------------------------------------------
__global__ __launch_bounds__(256) void transpose_k(
    const float* __restrict__ hm, float* __restrict__ planar)
{
    __shared__ float t[256][NCH + 1];   // stride 27 (odd) = conflict-free
    const int tid = threadIdx.x;
    const size_t base = (size_t)blockIdx.x * 256;   // pixel index
    const float* src = hm + base * NCH;
    for (int k = tid; k < 256 * NCH; k += 256) {
        t[k / NCH][k % NCH] = src[k];               // coalesced global read
    }
    __syncthreads();
    #pragma unroll
    for (int c = 0; c < NPART; c++)
        planar[(size_t)c * HWSZ + base + tid] = t[tid][c];  // coalesced write
}

// ---------------------------------------------------------------------------
// exact f64 separable blur value at tile-local pixel (r, c) (r=ly+dy, c=lx+dx),
// computed from the f32 LDS input tile. Caller guarantees in-image.
// in_t row for global row g is g-(y0-13); sm(y,x) needs rows y-12..y+12 ->
// in_t rows r+1..r+25, cols c+1..c+25 (all within [0,62)x[0,90) for
// r in [-1,32], c in [-1,64]).
// ---------------------------------------------------------------------------
__device__ double sm64_at(const float (*it)[LC], const double* w64, int r, int c)
{
    double acc = 0.0;
    for (int ci = 0; ci < 25; ci++) {
        double vv = 0.0;
        #pragma unroll
        for (int t = 0; t < 25; t++)
            vv = fma(w64[t], (double)it[r + 1 + t][c + 1 + ci], vv);
        acc = fma(w64[ci], vv, acc);
    }
    return acc;
}

// ---------------------------------------------------------------------------
// Kernel A: f32 separable blur + NMS screen with rigorous margin EPS;
// borderline pixels re-decided exactly in f64 from the same LDS tile.
// Candidates block-compacted (R3 pattern: one global atomic per block).
// ---------------------------------------------------------------------------
__global__ __launch_bounds__(256) void blur_peaks_f32(
    const float* __restrict__ planar,
    float* __restrict__ cval, int* __restrict__ cidx,
    int* __restrict__ counters, int cap)
{
    __shared__ float in_t[LRP][LC];        // 22.3 KB, live to the end
    __shared__ float v[VRR][VCS];          // 12.6 KB
    __shared__ float smv[SR][SCS];         // 9.1 KB
    __shared__ unsigned short cand[TH * TW];   // 4 KB  (local pixel ids)
    __shared__ unsigned short blist[TH * TW];  // 4 KB  (borderline: flags<<11 | pix)
    __shared__ double w64[2 * RAD + 1];
    __shared__ float  w32[2 * RAD + 1];
    __shared__ double wsum;
    __shared__ int lcount, bcount, gbase;

    const int tid = threadIdx.x;
    const int ch  = blockIdx.z;
    const int x0  = blockIdx.x * TW;
    const int y0  = blockIdx.y * TH;
    const float* plane = planar + (size_t)ch * HWSZ;

    if (tid == 0) { lcount = 0; bcount = 0; }

    // gaussian weights in f64 (same computation as the exact R1/R3 kernel)
    if (tid < 2 * RAD + 1) {
        double t = (double)(tid - RAD) / 3.0;
        w64[tid] = exp(-0.5 * t * t);
    }
    __syncthreads();
    if (tid == 0) {
        double s = 0.0;
        for (int i = 0; i < 2 * RAD + 1; i++) s += w64[i];
        wsum = s;
    }
    __syncthreads();
    if (tid < 2 * RAD + 1) {
        w64[tid] /= wsum;
        w32[tid] = (float)w64[tid];
    }

    // load input tile (coalesced planar rows, symmetric padding)
    for (int i = tid; i < LRP * LC; i += 256) {
        int r = i / LC, c = i % LC;
        int gy = symH(y0 - RAD - 1 + r);
        int gx = symW(x0 - RAD - 1 + c);
        in_t[r][c] = plane[(size_t)gy * W + gx];
    }
    __syncthreads();   // also covers weight normalization

    // vertical pass (f32): 9 row-groups of 4 x 90 cols, sliding-window reuse
    for (int seg = tid; seg < 9 * LC; seg += 256) {
        int c  = seg % LC;
        int r0 = (seg / LC) * 4;
        float a0 = 0.f, a1 = 0.f, a2 = 0.f, a3 = 0.f;
        #pragma unroll
        for (int t = 0; t < 28; t++) {
            float x = in_t[r0 + t][c];
            if (t < 25)            a0 = fmaf(w32[t],     x, a0);
            if (t >= 1 && t < 26)  a1 = fmaf(w32[t - 1], x, a1);
            if (t >= 2 && t < 27)  a2 = fmaf(w32[t - 2], x, a2);
            if (t >= 3)            a3 = fmaf(w32[t - 3], x, a3);
        }
        v[r0][c] = a0;
        if (r0 + 1 < VRR) v[r0 + 1][c] = a1;
        if (r0 + 2 < VRR) v[r0 + 2][c] = a2;
        if (r0 + 3 < VRR) v[r0 + 3][c] = a3;
    }
    __syncthreads();

    // horizontal pass (f32): 17 col-groups of 4 x 34 rows; OOB -> 0
    for (int seg = tid; seg < 17 * SR; seg += 256) {
        int r   = seg % SR;
        int cc0 = (seg / SR) * 4;
        int gy  = y0 - 1 + r;
        float a0 = 0.f, a1 = 0.f, a2 = 0.f, a3 = 0.f;
        #pragma unroll
        for (int t = 0; t < 28; t++) {
            float x = v[r][cc0 + t];
            if (t < 25)            a0 = fmaf(w32[t],     x, a0);
            if (t >= 1 && t < 26)  a1 = fmaf(w32[t - 1], x, a1);
            if (t >= 2 && t < 27)  a2 = fmaf(w32[t - 2], x, a2);
            if (t >= 3)            a3 = fmaf(w32[t - 3], x, a3);
        }
        bool rowok = (gy >= 0 && gy < H);
        { int cc = cc0;     if (cc < SC) { int gx = x0 - 1 + cc; smv[r][cc] = (rowok && gx >= 0 && gx < W) ? a0 : 0.f; } }
        { int cc = cc0 + 1; if (cc < SC) { int gx = x0 - 1 + cc; smv[r][cc] = (rowok && gx >= 0 && gx < W) ? a1 : 0.f; } }
        { int cc = cc0 + 2; if (cc < SC) { int gx = x0 - 1 + cc; smv[r][cc] = (rowok && gx >= 0 && gx < W) ? a2 : 0.f; } }
        { int cc = cc0 + 3; if (cc < SC) { int gx = x0 - 1 + cc; smv[r][cc] = (rowok && gx >= 0 && gx < W) ? a3 : 0.f; } }
    }
    __syncthreads();

    // screen: decide definite pixels; queue borderline ones with per-cmp flags
    for (int i = tid; i < TH * TW; i += 256) {
        int ly = i >> 6, lx = i & 63;
        int gy = y0 + ly;
        if (gy >= H) continue;          // W = 30*64 exactly; only y can overhang
        float s  = smv[ly + 1][lx + 1];
        float dT = s - 0.1f;
        float d0 = s - smv[ly][lx + 1];       // vs y-1  (m_left)
        float d1 = s - smv[ly + 2][lx + 1];   // vs y+1  (m_right)
        float d2 = s - smv[ly + 1][lx];       // vs x-1  (m_up)
        float d3 = s - smv[ly + 1][lx + 2];   // vs x+1  (m_down)
        int flags = (fabsf(dT) <= EPS ? 1 : 0)
                  | (fabsf(d0) <= EPS ? 2 : 0)
                  | (fabsf(d1) <= EPS ? 4 : 0)
                  | (fabsf(d2) <= EPS ? 8 : 0)
                  | (fabsf(d3) <= EPS ? 16 : 0);
        if (!flags) {
            if (dT > 0.f && d0 >= 0.f && d1 >= 0.f && d2 >= 0.f && d3 >= 0.f) {
                int pos = atomicAdd(&lcount, 1);
                cand[pos] = (unsigned short)((ly << 6) | lx);
            }
        } else {
            bool fail = (!(flags & 1)  && dT <= 0.f) ||
                        (!(flags & 2)  && d0 <  0.f) ||
                        (!(flags & 4)  && d1 <  0.f) ||
                        (!(flags & 8)  && d2 <  0.f) ||
                        (!(flags & 16) && d3 <  0.f);
            if (!fail) {
                int bp = atomicAdd(&bcount, 1);
                blist[bp] = (unsigned short)((flags << 11) | (ly << 6) | lx);
            }
        }
    }
    __syncthreads();

    // f64 recheck of borderline pixels (one lane each, data in LDS already)
    int nb = bcount;
    for (int p = tid; p < nb; p += 256) {
        int e = blist[p];
        int flags = e >> 11;
        int ly = (e >> 6) & 31, lx = e & 63;
        int gy = y0 + ly, gx = x0 + lx;
        double sC = sm64_at(in_t, w64, ly, lx);
        float  sF = smv[ly + 1][lx + 1];
        bool ok = (flags & 1) ? (sC > 0.1) : (sF > 0.1f);
        if (ok) {
            if (flags & 2) { double n = (gy - 1 >= 0) ? sm64_at(in_t, w64, ly - 1, lx) : 0.0; ok = (sC >= n); }
            else           ok = (sF >= smv[ly][lx + 1]);
        }
        if (ok) {
            if (flags & 4) { double n = (gy + 1 < H)  ? sm64_at(in_t, w64, ly + 1, lx) : 0.0; ok = (sC >= n); }
            else           ok = (sF >= smv[ly + 2][lx + 1]);
        }
        if (ok) {
            if (flags & 8) { double n = (gx - 1 >= 0) ? sm64_at(in_t, w64, ly, lx - 1) : 0.0; ok = (sC >= n); }
            else           ok = (sF >= smv[ly + 1][lx]);
        }
        if (ok) {
            if (flags & 16){ double n = (gx + 1 < W)  ? sm64_at(in_t, w64, ly, lx + 1) : 0.0; ok = (sC >= n); }
            else           ok = (sF >= smv[ly + 1][lx + 2]);
        }
        if (ok) {
            int pos = atomicAdd(&lcount, 1);
            cand[pos] = (unsigned short)((ly << 6) | lx);
        }
    }
    __syncthreads();

    // one global atomic per block, then coalesced copy-out
    if (tid == 0) gbase = atomicAdd(&counters[ch], lcount);
    __syncthreads();
    int n = lcount, b = gbase;
    for (int i = tid; i < n; i += 256) {
        int p = b + i;
        if (p < cap) {
            int e = cand[i];
            int ly = (e >> 6) & 31, lx = e & 63;
            cval[(size_t)ch * cap + p] = in_t[ly + RAD + 1][lx + RAD + 1];  // original bits
            cidx[(size_t)ch * cap + p] = (y0 + ly) * W + (x0 + lx);
        }
    }
}

// ---------------------------------------------------------------------------
// Kernel A-fallback: round-1 gather version (used only if ws too small)
// ---------------------------------------------------------------------------
#define LR (TH + 2*RAD + 2)
#define VC (TW + 2*RAD + 2)
__global__ __launch_bounds__(256) void blur_peaks_gather(
    const float* __restrict__ hm,
    float* __restrict__ cval, int* __restrict__ cidx,
    int* __restrict__ counters, int cap)
{
    __shared__ float  in_t[LR][LC];
    __shared__ double v[VRR][VC];
    __shared__ double smv[SR][SC];
    __shared__ double wgt[2 * RAD + 1];
    __shared__ double wsum;

    const int tid = threadIdx.x;
    const int ch  = blockIdx.x;
    const int x0  = blockIdx.y * TW;
    const int y0  = blockIdx.z * TH;

    if (tid < 2 * RAD + 1) {
        double t = (double)(tid - RAD) / 3.0;
        wgt[tid] = exp(-0.5 * t * t);
    }
    __syncthreads();
    if (tid == 0) {
        double s = 0.0;
        for (int i = 0; i < 2 * RAD + 1; i++) s += wgt[i];
        wsum = s;
    }
    __syncthreads();
    if (tid < 2 * RAD + 1) wgt[tid] /= wsum;

    for (int i = tid; i < LR * LC; i += 256) {
        int r = i / LC, c = i % LC;
        int gy = symH(y0 - RAD - 1 + r);
        int gx = symW(x0 - RAD - 1 + c);
        in_t[r][c] = hm[((size_t)gy * W + gx) * NCH + ch];
    }
    __syncthreads();

    for (int i = tid; i < VRR * VC; i += 256) {
        int r = i / VC, c = i % VC;
        double acc = 0.0;
        #pragma unroll
        for (int t = 0; t < 2 * RAD + 1; t++)
            acc = fma(wgt[t], (double)in_t[r + t][c], acc);
        v[r][c] = acc;
    }
    __syncthreads();

    for (int i = tid; i < SR * SC; i += 256) {
        int r = i / SC, cc = i % SC;
        int gy = y0 - 1 + r;
        int gx = x0 - 1 + cc;
        double acc = 0.0;
        if (gy >= 0 && gy < H && gx >= 0 && gx < W) {
            #pragma unroll
            for (int t = 0; t < 2 * RAD + 1; t++)
                acc = fma(wgt[t], v[r][cc + t], acc);
        }
        smv[r][cc] = acc;
    }
    __syncthreads();

    for (int i = tid; i < TH * TW; i += 256) {
        int ly = i / TW, lx = i % TW;
        int gy = y0 + ly, gx = x0 + lx;
        if (gy >= H || gx >= W) continue;
        double s = smv[ly + 1][lx + 1];
        if (s > 0.1 &&
            s >= smv[ly][lx + 1] && s >= smv[ly + 2][lx + 1] &&
            s >= smv[ly + 1][lx] && s >= smv[ly + 1][lx + 2]) {
            float val = in_t[ly + RAD + 1][lx + RAD + 1];
            int pos = atomicAdd(&counters[ch], 1);
            if (pos < cap) {
                cval[(size_t)ch * cap + pos] = val;
                cidx[(size_t)ch * cap + pos] = gy * W + gx;
            }
        }
    }
}

// ---------------------------------------------------------------------------
// Kernel B: per-channel exact top-32 by (value desc, index asc)
// ---------------------------------------------------------------------------
#define BT 128
__global__ __launch_bounds__(BT) void topk_kernel(
    const float* __restrict__ cval, const int* __restrict__ cidx,
    const int* __restrict__ counters, int cap, float* __restrict__ out)
{
    __shared__ unsigned long long lk[KTOP * BT];
    __shared__ unsigned long long rk[BT];
    __shared__ int rw[BT];
    __shared__ int winner;

    const int tid = threadIdx.x;
    const int ch  = blockIdx.x;
    int n = counters[ch];
    if (n > cap) n = cap;

    int cnt = 0;
    for (int j = tid; j < n; j += BT) {
        float v = cval[(size_t)ch * cap + j];
        unsigned int u = __float_as_uint(v);
        u = (u & 0x80000000u) ? ~u : (u | 0x80000000u);
        unsigned long long key =
            ((unsigned long long)u << 32) |
            (unsigned int)(0xFFFFFFFFu - (unsigned int)cidx[(size_t)ch * cap + j]);
        if (cnt == KTOP) {
            if (key <= lk[(KTOP - 1) * BT + tid]) continue;
            cnt = KTOP - 1;
        }
        int i = cnt;
        while (i > 0 && key > lk[(i - 1) * BT + tid]) {
            lk[i * BT + tid] = lk[(i - 1) * BT + tid];
            i--;
        }
        lk[i * BT + tid] = key;
        cnt++;
    }
    int cur = 0;
    __syncthreads();

    for (int k = 0; k < KTOP; k++) {
        rk[tid] = (cur < cnt) ? lk[cur * BT + tid] : 0ULL;
        rw[tid] = tid;
        __syncthreads();
        for (int s = BT / 2; s > 0; s >>= 1) {
            if (tid < s) {
                if (rk[tid + s] > rk[tid]) { rk[tid] = rk[tid + s]; rw[tid] = rw[tid + s]; }
            }
            __syncthreads();
        }
        if (tid == 0) {
            winner = rw[0];
            unsigned long long bk = rk[0];
            float px, py, sc, mk;
            if (bk == 0ULL) {
                int fake = k - n; if (fake < 0) fake = 0;
                px = (float)(fake % W); py = (float)(fake / W); sc = 0.f; mk = 0.f;
            } else {
                unsigned int u = (unsigned int)(bk >> 32);
                unsigned int fb = (u & 0x80000000u) ? (u ^ 0x80000000u) : ~u;
                float v = __uint_as_float(fb);
                int idx = (int)(0xFFFFFFFFu - (unsigned int)(bk & 0xFFFFFFFFu));
                px = (float)(idx % W); py = (float)(idx / W); sc = v; mk = 1.f;
            }
            out[ch * KTOP + k]          = px;
            out[OFF_PY + ch * KTOP + k] = py;
            out[OFF_SC + ch * KTOP + k] = sc;
            out[OFF_MK + ch * KTOP + k] = mk;
        }
        __syncthreads();
        if (tid == winner && cur < cnt) cur++;
        __syncthreads();
    }
}

// ---------------------------------------------------------------------------
// Kernel C: limb connection scores (26 x 32 x 32)
// ---------------------------------------------------------------------------
__global__ __launch_bounds__(1024) void limbs_kernel(
    const float* __restrict__ pk, const float* __restrict__ paf,
    float* __restrict__ out)
{
    const int l = blockIdx.x;
    const int tid = threadIdx.x;
    const int i = tid >> 5;
    const int j = tid & 31;
    const int A = LIMBS_d[2 * l], B = LIMBS_d[2 * l + 1];

    float ax = pk[A * KTOP + i],          ay = pk[OFF_PY + A * KTOP + i];
    float ma = pk[OFF_MK + A * KTOP + i];
    float bx = pk[B * KTOP + j],          by = pk[OFF_PY + B * KTOP + j];
    float mb = pk[OFF_MK + B * KTOP + j];

    float vx = bx - ax, vy = by - ay;
    float norm = sqrtf(vx * vx + vy * vy) + 1e-10f;
    float ux = vx / norm, uy = vy / norm;

    const float step = 1.0f / 9.0f;
    float sum = 0.f;
    #pragma unroll
    for (int m = 0; m < MID; m++) {
        float t = (float)m * step;
        int sx = (int)rintf(ax + vx * t);
        int sy = (int)rintf(ay + vy * t);
        const float* p = paf + ((size_t)sy * W + sx) * (2 * NLIMB) + 2 * l;
        sum += p[0] * ux + p[1] * uy;
    }
    float score = sum / (float)MID;
    score = score < 0.f ? 0.f : (score > 1.f ? 1.f : score);
    float res = (ma != 0.f && mb != 0.f) ? score : 0.f;
    out[OFF_CONN + l * (KTOP * KTOP) + i * KTOP + j] = res;
}

// ---------------------------------------------------------------------------
extern "C" void kernel_launch(void* const* d_in, const int* in_sizes, int n_in,
                              void* d_out, int out_size, void* d_ws, size_t ws_size,
                              hipStream_t stream)
{
    const float* hm  = (const float*)d_in[0];
    const float* paf = (const float*)d_in[1];
    float* out = (float*)d_out;

    const size_t planar_bytes = (size_t)NPART * HWSZ * sizeof(float);  // ~207.4 MB
    const size_t head = 256;

    bool pathA = false;
    int cap = 1;
    if (ws_size > head + planar_bytes + (size_t)NPART * 8 * 4096) {
        size_t avail = ws_size - head - planar_bytes;
        long long c = (long long)(avail / ((size_t)NPART * 8));
        cap = c > 65536 ? 65536 : (int)c;
        pathA = true;
    } else {
        size_t avail = ws_size > head ? ws_size - head : 0;
        long long c = (long long)(avail / ((size_t)NPART * 8));
        cap = c > 65536 ? 65536 : (int)c;
        if (cap < 1) cap = 1;
    }

    int*   counters = (int*)d_ws;
    float* cval = (float*)((char*)d_ws + head);
    int*   cidx = (int*)(cval + (size_t)NPART * cap);
    float* planar = (float*)(cidx + (size_t)NPART * cap);
    planar = (float*)(((uintptr_t)planar + 255) & ~(uintptr_t)255);

    hipMemsetAsync(d_ws, 0, head, stream);

    if (pathA) {
        transpose_k<<<HWSZ / 256, 256, 0, stream>>>(hm, planar);
        dim3 gA(W / TW, (H + TH - 1) / TH, NPART);
        blur_peaks_f32<<<gA, 256, 0, stream>>>(planar, cval, cidx, counters, cap);
    } else {
        dim3 gA(NPART, (W + TW - 1) / TW, (H + TH - 1) / TH);
        blur_peaks_gather<<<gA, 256, 0, stream>>>(hm, cval, cidx, counters, cap);
    }
    topk_kernel<<<NPART, BT, 0, stream>>>(cval, cidx, counters, cap, out);
    limbs_kernel<<<NLIMB, 1024, 0, stream>>>(out, paf, out);
}

// Round 5
// 929.507 us; speedup vs baseline: 1.1116x; 1.1116x over previous
//
#include <hip/hip_runtime.h>
#include <math.h>
#include <float.h>

#define H 1080
#define W 1920
#define HWSZ (H*W)
#define NPART 25
#define NCH 26          // heatmap channels in memory (NPART+1)
#define NLIMB 26
#define KTOP 32
#define MID 10
#define RAD 12

// Tile geometry for fused blur+peak kernel
#define TH 32
#define TW 64
#define LRP 58               // input rows: y0-13 .. y0+44 (exact need)
#define LC  90               // input cols: x0-13 .. x0+76
#define VRR 34               // vertical-blur rows (y0-1 .. y0+32)
#define VCS 93               // v col stride (93%32=29, coprime -> bank spread)
#define SR  34               // sm rows
#define SC  66               // sm cols (real)
#define SCS 68               // smv col stride

#define EPS 1.2e-5f          // screen margin; hard two-sided f32 bound ~7e-6
#define BLCAP (1 << 20)      // global borderline-entry capacity (4 MB)

// Output layout (floats): px[25*32] py[25*32] score[25*32] mask[25*32] conn[26*32*32]
#define OFF_PY   800
#define OFF_SC   1600
#define OFF_MK   2400
#define OFF_CONN 3200

__device__ __constant__ int LIMBS_d[NLIMB * 2] = {
    1,8, 1,2, 1,5, 2,3, 3,4, 5,6, 6,7, 8,9, 9,10, 10,11, 8,12, 12,13, 13,14,
    1,0, 0,15, 15,16, 0,17, 0,18, 14,19, 19,20, 14,21, 11,22, 22,23, 11,24, 2,17, 5,18
};

__device__ __forceinline__ int symH(int y) {
    if (y < 0) return -1 - y;
    if (y >= H) return 2 * H - 1 - y;
    return y;
}
__device__ __forceinline__ int symW(int x) {
    if (x < 0) return -1 - x;
    if (x >= W) return 2 * W - 1 - x;
    return x;
}

// ---------------------------------------------------------------------------
// Kernel T: channels-last (H,W,26) -> 25 planar (H,W) f32 images (bit-exact)
// ---------------------------------------------------------------------------
__global__ __launch_bounds__(256) void transpose_k(
    const float* __restrict__ hm, float* __restrict__ planar)
{
    __shared__ float t[256][NCH + 1];   // stride 27 (odd) = conflict-free
    const int tid = threadIdx.x;
    const size_t base = (size_t)blockIdx.x * 256;   // pixel index
    const float* src = hm + base * NCH;
    for (int k = tid; k < 256 * NCH; k += 256) {
        t[k / NCH][k % NCH] = src[k];               // coalesced global read
    }
    __syncthreads();
    #pragma unroll
    for (int c = 0; c < NPART; c++)
        planar[(size_t)c * HWSZ + base + tid] = t[tid][c];  // coalesced write
}

// ---------------------------------------------------------------------------
// Kernel A (v5): all-f32 separable blur + NMS screen with margin EPS.
// Borderline pixels are EMITTED to a global list (block-compacted) and
// re-decided by recheck_k in f64 — no serial f64 tail in this kernel.
// LDS <= 40KB -> 4 blocks/CU.
// ---------------------------------------------------------------------------
__global__ __launch_bounds__(256) void blur_peaks_v5(
    const float* __restrict__ planar,
    float* __restrict__ cval, int* __restrict__ cidx,
    int* __restrict__ counters, unsigned int* __restrict__ blg, int cap)
{
    union U {
        float in_t[LRP][LC];    // 20.9 KB — consumed by vertical pass
        float smv[SR][SCS];     // 9.2 KB  — overlaid after vertical done
    };
    __shared__ U u;
    __shared__ float v[VRR][VCS];          // 12.6 KB
    __shared__ double w64[2 * RAD + 1];    // 200 B (weight derivation only)
    __shared__ float  w32[2 * RAD + 1];
    __shared__ double wsum;
    __shared__ unsigned short cand[TH * TW];   // 4 KB
    __shared__ unsigned short bl[1024];        // 2 KB
    __shared__ int lcount, bcount, gbase, gbase2;

    const int tid = threadIdx.x;
    const int ch  = blockIdx.z;
    const int x0  = blockIdx.x * TW;
    const int y0  = blockIdx.y * TH;
    const float* plane = planar + (size_t)ch * HWSZ;

    if (tid == 0) { lcount = 0; bcount = 0; }

    // gaussian weights: f64 derivation (matches np), f32 working copy
    if (tid < 2 * RAD + 1) {
        double t = (double)(tid - RAD) / 3.0;
        w64[tid] = exp(-0.5 * t * t);
    }
    __syncthreads();
    if (tid == 0) {
        double s = 0.0;
        for (int i = 0; i < 2 * RAD + 1; i++) s += w64[i];
        wsum = s;
    }
    __syncthreads();
    if (tid < 2 * RAD + 1) w32[tid] = (float)(w64[tid] / wsum);

    // load input tile (coalesced planar rows, symmetric padding)
    for (int i = tid; i < LRP * LC; i += 256) {
        int r = i / LC, c = i % LC;
        int gy = symH(y0 - RAD - 1 + r);
        int gx = symW(x0 - RAD - 1 + c);
        u.in_t[r][c] = plane[(size_t)gy * W + gx];
    }
    __syncthreads();   // also covers weight normalization

    // vertical pass: 4 row-groups of 8 (rows 0..31), sliding-window reuse
    for (int seg = tid; seg < 4 * LC; seg += 256) {
        int g = seg / LC, c = seg % LC;
        int r0 = g * 8;
        float a0=0.f,a1=0.f,a2=0.f,a3=0.f,a4=0.f,a5=0.f,a6=0.f,a7=0.f;
        #pragma unroll
        for (int t = 0; t < 32; t++) {          // reads rows r0..r0+31 <= 55
            float x = u.in_t[r0 + t][c];
            if (t < 25)            a0 = fmaf(w32[t],     x, a0);
            if (t >= 1 && t < 26)  a1 = fmaf(w32[t - 1], x, a1);
            if (t >= 2 && t < 27)  a2 = fmaf(w32[t - 2], x, a2);
            if (t >= 3 && t < 28)  a3 = fmaf(w32[t - 3], x, a3);
            if (t >= 4 && t < 29)  a4 = fmaf(w32[t - 4], x, a4);
            if (t >= 5 && t < 30)  a5 = fmaf(w32[t - 5], x, a5);
            if (t >= 6 && t < 31)  a6 = fmaf(w32[t - 6], x, a6);
            if (t >= 7)            a7 = fmaf(w32[t - 7], x, a7);
        }
        v[r0    ][c] = a0; v[r0 + 1][c] = a1; v[r0 + 2][c] = a2; v[r0 + 3][c] = a3;
        v[r0 + 4][c] = a4; v[r0 + 5][c] = a5; v[r0 + 6][c] = a6; v[r0 + 7][c] = a7;
    }
    // last 2 rows (32, 33): reads rows 32..57
    for (int c = tid; c < LC; c += 256) {
        float a0 = 0.f, a1 = 0.f;
        #pragma unroll
        for (int t = 0; t < 26; t++) {
            float x = u.in_t[32 + t][c];
            if (t < 25)  a0 = fmaf(w32[t],     x, a0);
            if (t >= 1)  a1 = fmaf(w32[t - 1], x, a1);
        }
        v[32][c] = a0; v[33][c] = a1;
    }
    __syncthreads();   // in_t fully consumed; smv may overlay it now

    // horizontal pass: 8 col-groups of 8 + 1 of 4; r fastest (bank spread)
    for (int seg = tid; seg < 8 * SR; seg += 256) {
        int r   = seg % SR;
        int cc0 = (seg / SR) * 8;
        int gy  = y0 - 1 + r;
        bool rowok = (gy >= 0 && gy < H);
        float a0=0.f,a1=0.f,a2=0.f,a3=0.f,a4=0.f,a5=0.f,a6=0.f,a7=0.f;
        #pragma unroll
        for (int t = 0; t < 32; t++) {          // reads cols cc0..cc0+31 <= 87
            float x = v[r][cc0 + t];
            if (t < 25)            a0 = fmaf(w32[t],     x, a0);
            if (t >= 1 && t < 26)  a1 = fmaf(w32[t - 1], x, a1);
            if (t >= 2 && t < 27)  a2 = fmaf(w32[t - 2], x, a2);
            if (t >= 3 && t < 28)  a3 = fmaf(w32[t - 3], x, a3);
            if (t >= 4 && t < 29)  a4 = fmaf(w32[t - 4], x, a4);
            if (t >= 5 && t < 30)  a5 = fmaf(w32[t - 5], x, a5);
            if (t >= 6 && t < 31)  a6 = fmaf(w32[t - 6], x, a6);
            if (t >= 7)            a7 = fmaf(w32[t - 7], x, a7);
        }
        float av[8] = {a0,a1,a2,a3,a4,a5,a6,a7};
        #pragma unroll
        for (int k = 0; k < 8; k++) {
            int cc = cc0 + k;
            int gx = x0 - 1 + cc;
            u.smv[r][cc] = (rowok && gx >= 0 && gx < W) ? av[k] : 0.f;
        }
    }
    // last 4 cols (64..67; only 64,65 real)
    for (int r = tid; r < SR; r += 256) {
        int gy = y0 - 1 + r;
        bool rowok = (gy >= 0 && gy < H);
        float a0 = 0.f, a1 = 0.f;
        #pragma unroll
        for (int t = 0; t < 26; t++) {          // reads cols 64..89
            float x = v[r][64 + t];
            if (t < 25)  a0 = fmaf(w32[t],     x, a0);
            if (t >= 1)  a1 = fmaf(w32[t - 1], x, a1);
        }
        { int gx = x0 + 63; u.smv[r][64] = (rowok && gx < W) ? a0 : 0.f; }
        { int gx = x0 + 64; u.smv[r][65] = (rowok && gx < W) ? a1 : 0.f; }
    }
    __syncthreads();

    // screen: 8 px/thread with register reuse; definite -> cand, borderline -> bl
    {
        int ly = tid >> 3, lx0 = (tid & 7) << 3;
        int gy = y0 + ly;
        if (gy < H) {
            float cr[10], ur[8], dr[8];
            #pragma unroll
            for (int k = 0; k < 10; k++) cr[k] = u.smv[ly + 1][lx0 + k];
            #pragma unroll
            for (int k = 0; k < 8; k++) {
                ur[k] = u.smv[ly][lx0 + 1 + k];
                dr[k] = u.smv[ly + 2][lx0 + 1 + k];
            }
            #pragma unroll
            for (int j = 0; j < 8; j++) {
                int lx = lx0 + j;
                float s  = cr[j + 1];
                float dT = s - 0.1f;
                float d0 = s - ur[j];          // vs y-1
                float d1 = s - dr[j];          // vs y+1
                float d2 = s - cr[j];          // vs x-1
                float d3 = s - cr[j + 2];      // vs x+1
                int flags = (fabsf(dT) <= EPS ? 1 : 0)
                          | (fabsf(d0) <= EPS ? 2 : 0)
                          | (fabsf(d1) <= EPS ? 4 : 0)
                          | (fabsf(d2) <= EPS ? 8 : 0)
                          | (fabsf(d3) <= EPS ? 16 : 0);
                if (!flags) {
                    if (dT > 0.f && d0 >= 0.f && d1 >= 0.f && d2 >= 0.f && d3 >= 0.f) {
                        int pos = atomicAdd(&lcount, 1);
                        cand[pos] = (unsigned short)((ly << 6) | lx);
                    }
                } else {
                    bool fail = (!(flags & 1)  && dT <= 0.f) ||
                                (!(flags & 2)  && d0 <  0.f) ||
                                (!(flags & 4)  && d1 <  0.f) ||
                                (!(flags & 8)  && d2 <  0.f) ||
                                (!(flags & 16) && d3 <  0.f);
                    if (!fail) {
                        int bp = atomicAdd(&bcount, 1);
                        unsigned short e16 = (unsigned short)((flags << 11) | (ly << 6) | lx);
                        if (bp < 1024) bl[bp] = e16;
                        else {   // rare overflow: write straight to global list
                            int gp = atomicAdd(&counters[32], 1);
                            if (gp < BLCAP)
                                blg[gp] = ((unsigned int)ch << 26) | ((unsigned int)flags << 21)
                                        | (unsigned int)(gy * W + (x0 + lx));
                        }
                    }
                }
            }
        }
    }
    __syncthreads();

    // one global atomic per block per list, then coalesced copy-out
    if (tid == 0) {
        gbase  = atomicAdd(&counters[ch], lcount);
        int nb = bcount < 1024 ? bcount : 1024;
        gbase2 = atomicAdd(&counters[32], nb);
    }
    __syncthreads();
    int n = lcount, b = gbase;
    for (int i = tid; i < n; i += 256) {
        int p = b + i;
        if (p < cap) {
            int e = cand[i];
            int ly = (e >> 6) & 31, lx = e & 63;
            int gpix = (y0 + ly) * W + (x0 + lx);
            cval[(size_t)ch * cap + p] = plane[gpix];   // original bits
            cidx[(size_t)ch * cap + p] = gpix;
        }
    }
    int nb = bcount < 1024 ? bcount : 1024;
    for (int i = tid; i < nb; i += 256) {
        int gp = gbase2 + i;
        if (gp < BLCAP) {
            int e = bl[i];
            int flags = e >> 11;
            int ly = (e >> 6) & 31, lx = e & 63;
            blg[gp] = ((unsigned int)ch << 26) | ((unsigned int)flags << 21)
                    | (unsigned int)((y0 + ly) * W + (x0 + lx));
        }
    }
}

// ---------------------------------------------------------------------------
// Kernel R: f64 recheck of borderline pixels. One wave per block; lanes 0..24
// compute vertical column sums (preloaded global reads), shfl-chain horizontal.
// Only FLAGGED comparisons are re-decided (unflagged ones were proven in f32).
// ---------------------------------------------------------------------------
__device__ double sm64_eval(const float* __restrict__ plane, const double* w64s,
                            int y, int x)
{
    int lane = threadIdx.x & 63;
    double colsum = 0.0;
    if (lane < 25) {
        int cx = symW(x - RAD + lane);
        float xv[25];
        #pragma unroll
        for (int t = 0; t < 25; t++) {
            int ry = symH(y - RAD + t);
            xv[t] = plane[(size_t)ry * W + cx];
        }
        #pragma unroll
        for (int t = 0; t < 25; t++)
            colsum = fma(w64s[t], (double)xv[t], colsum);
    }
    double acc = 0.0;
    for (int ci = 0; ci < 25; ci++) {
        double cs = __shfl(colsum, ci, 64);
        acc = fma(w64s[ci], cs, acc);
    }
    return acc;   // identical on all lanes
}

__global__ __launch_bounds__(64) void recheck_k(
    const float* __restrict__ planar,
    float* __restrict__ cval, int* __restrict__ cidx,
    int* __restrict__ counters, const unsigned int* __restrict__ blg, int cap)
{
    __shared__ double w64s[2 * RAD + 1];
    __shared__ double wsum;
    const int tid = threadIdx.x;
    if (tid < 2 * RAD + 1) {
        double t = (double)(tid - RAD) / 3.0;
        w64s[tid] = exp(-0.5 * t * t);
    }
    __syncthreads();
    if (tid == 0) {
        double s = 0.0;
        for (int i = 0; i < 2 * RAD + 1; i++) s += w64s[i];
        wsum = s;
    }
    __syncthreads();
    if (tid < 2 * RAD + 1) w64s[tid] /= wsum;
    __syncthreads();

    int total = counters[32];
    if (total > BLCAP) total = BLCAP;
    for (int e = blockIdx.x; e < total; e += gridDim.x) {
        unsigned int ent = blg[e];
        int ch    = (int)(ent >> 26);
        int flags = (int)((ent >> 21) & 31);
        int gpix  = (int)(ent & 0x1FFFFFu);
        int gy = gpix / W, gx = gpix - gy * W;
        const float* plane = planar + (size_t)ch * HWSZ;
        double sc = sm64_eval(plane, w64s, gy, gx);
        bool ok = (flags & 1) ? (sc > 0.1) : true;
        if (ok && (flags & 2))  { double nv = (gy - 1 >= 0) ? sm64_eval(plane, w64s, gy - 1, gx) : 0.0; ok = (sc >= nv); }
        if (ok && (flags & 4))  { double nv = (gy + 1 <  H) ? sm64_eval(plane, w64s, gy + 1, gx) : 0.0; ok = (sc >= nv); }
        if (ok && (flags & 8))  { double nv = (gx - 1 >= 0) ? sm64_eval(plane, w64s, gy, gx - 1) : 0.0; ok = (sc >= nv); }
        if (ok && (flags & 16)) { double nv = (gx + 1 <  W) ? sm64_eval(plane, w64s, gy, gx + 1) : 0.0; ok = (sc >= nv); }
        if (tid == 0 && ok) {
            int p = atomicAdd(&counters[ch], 1);
            if (p < cap) {
                cval[(size_t)ch * cap + p] = plane[gpix];
                cidx[(size_t)ch * cap + p] = gpix;
            }
        }
    }
}

// ---------------------------------------------------------------------------
// Kernel A-fallback: exact-f64 gather version (used only if ws too small)
// ---------------------------------------------------------------------------
#define LR (TH + 2*RAD + 2)
#define VC (TW + 2*RAD + 2)
__global__ __launch_bounds__(256) void blur_peaks_gather(
    const float* __restrict__ hm,
    float* __restrict__ cval, int* __restrict__ cidx,
    int* __restrict__ counters, int cap)
{
    __shared__ float  in_t[LR][LC];
    __shared__ double v[VRR][VC];
    __shared__ double smv[SR][SC];
    __shared__ double wgt[2 * RAD + 1];
    __shared__ double wsum;

    const int tid = threadIdx.x;
    const int ch  = blockIdx.x;
    const int x0  = blockIdx.y * TW;
    const int y0  = blockIdx.z * TH;

    if (tid < 2 * RAD + 1) {
        double t = (double)(tid - RAD) / 3.0;
        wgt[tid] = exp(-0.5 * t * t);
    }
    __syncthreads();
    if (tid == 0) {
        double s = 0.0;
        for (int i = 0; i < 2 * RAD + 1; i++) s += wgt[i];
        wsum = s;
    }
    __syncthreads();
    if (tid < 2 * RAD + 1) wgt[tid] /= wsum;

    for (int i = tid; i < LR * LC; i += 256) {
        int r = i / LC, c = i % LC;
        int gy = symH(y0 - RAD - 1 + r);
        int gx = symW(x0 - RAD - 1 + c);
        in_t[r][c] = hm[((size_t)gy * W + gx) * NCH + ch];
    }
    __syncthreads();

    for (int i = tid; i < VRR * VC; i += 256) {
        int r = i / VC, c = i % VC;
        double acc = 0.0;
        #pragma unroll
        for (int t = 0; t < 2 * RAD + 1; t++)
            acc = fma(wgt[t], (double)in_t[r + t][c], acc);
        v[r][c] = acc;
    }
    __syncthreads();

    for (int i = tid; i < SR * SC; i += 256) {
        int r = i / SC, cc = i % SC;
        int gy = y0 - 1 + r;
        int gx = x0 - 1 + cc;
        double acc = 0.0;
        if (gy >= 0 && gy < H && gx >= 0 && gx < W) {
            #pragma unroll
            for (int t = 0; t < 2 * RAD + 1; t++)
                acc = fma(wgt[t], v[r][cc + t], acc);
        }
        smv[r][cc] = acc;
    }
    __syncthreads();

    for (int i = tid; i < TH * TW; i += 256) {
        int ly = i / TW, lx = i % TW;
        int gy = y0 + ly, gx = x0 + lx;
        if (gy >= H || gx >= W) continue;
        double s = smv[ly + 1][lx + 1];
        if (s > 0.1 &&
            s >= smv[ly][lx + 1] && s >= smv[ly + 2][lx + 1] &&
            s >= smv[ly + 1][lx] && s >= smv[ly + 1][lx + 2]) {
            float val = in_t[ly + RAD + 1][lx + RAD + 1];
            int pos = atomicAdd(&counters[ch], 1);
            if (pos < cap) {
                cval[(size_t)ch * cap + pos] = val;
                cidx[(size_t)ch * cap + pos] = gy * W + gx;
            }
        }
    }
}

// ---------------------------------------------------------------------------
// Kernel B: per-channel exact top-32 by (value desc, index asc)
// ---------------------------------------------------------------------------
#define BT 128
__global__ __launch_bounds__(BT) void topk_kernel(
    const float* __restrict__ cval, const int* __restrict__ cidx,
    const int* __restrict__ counters, int cap, float* __restrict__ out)
{
    __shared__ unsigned long long lk[KTOP * BT];
    __shared__ unsigned long long rk[BT];
    __shared__ int rw[BT];
    __shared__ int winner;

    const int tid = threadIdx.x;
    const int ch  = blockIdx.x;
    int n = counters[ch];
    if (n > cap) n = cap;

    int cnt = 0;
    for (int j = tid; j < n; j += BT) {
        float v = cval[(size_t)ch * cap + j];
        unsigned int u = __float_as_uint(v);
        u = (u & 0x80000000u) ? ~u : (u | 0x80000000u);
        unsigned long long key =
            ((unsigned long long)u << 32) |
            (unsigned int)(0xFFFFFFFFu - (unsigned int)cidx[(size_t)ch * cap + j]);
        if (cnt == KTOP) {
            if (key <= lk[(KTOP - 1) * BT + tid]) continue;
            cnt = KTOP - 1;
        }
        int i = cnt;
        while (i > 0 && key > lk[(i - 1) * BT + tid]) {
            lk[i * BT + tid] = lk[(i - 1) * BT + tid];
            i--;
        }
        lk[i * BT + tid] = key;
        cnt++;
    }
    int cur = 0;
    __syncthreads();

    for (int k = 0; k < KTOP; k++) {
        rk[tid] = (cur < cnt) ? lk[cur * BT + tid] : 0ULL;
        rw[tid] = tid;
        __syncthreads();
        for (int s = BT / 2; s > 0; s >>= 1) {
            if (tid < s) {
                if (rk[tid + s] > rk[tid]) { rk[tid] = rk[tid + s]; rw[tid] = rw[tid + s]; }
            }
            __syncthreads();
        }
        if (tid == 0) {
            winner = rw[0];
            unsigned long long bk = rk[0];
            float px, py, sc, mk;
            if (bk == 0ULL) {
                int fake = k - n; if (fake < 0) fake = 0;
                px = (float)(fake % W); py = (float)(fake / W); sc = 0.f; mk = 0.f;
            } else {
                unsigned int u = (unsigned int)(bk >> 32);
                unsigned int fb = (u & 0x80000000u) ? (u ^ 0x80000000u) : ~u;
                float v = __uint_as_float(fb);
                int idx = (int)(0xFFFFFFFFu - (unsigned int)(bk & 0xFFFFFFFFu));
                px = (float)(idx % W); py = (float)(idx / W); sc = v; mk = 1.f;
            }
            out[ch * KTOP + k]          = px;
            out[OFF_PY + ch * KTOP + k] = py;
            out[OFF_SC + ch * KTOP + k] = sc;
            out[OFF_MK + ch * KTOP + k] = mk;
        }
        __syncthreads();
        if (tid == winner && cur < cnt) cur++;
        __syncthreads();
    }
}

// ---------------------------------------------------------------------------
// Kernel C: limb connection scores (26 x 32 x 32)
// ---------------------------------------------------------------------------
__global__ __launch_bounds__(1024) void limbs_kernel(
    const float* __restrict__ pk, const float* __restrict__ paf,
    float* __restrict__ out)
{
    const int l = blockIdx.x;
    const int tid = threadIdx.x;
    const int i = tid >> 5;
    const int j = tid & 31;
    const int A = LIMBS_d[2 * l], B = LIMBS_d[2 * l + 1];

    float ax = pk[A * KTOP + i],          ay = pk[OFF_PY + A * KTOP + i];
    float ma = pk[OFF_MK + A * KTOP + i];
    float bx = pk[B * KTOP + j],          by = pk[OFF_PY + B * KTOP + j];
    float mb = pk[OFF_MK + B * KTOP + j];

    float vx = bx - ax, vy = by - ay;
    float norm = sqrtf(vx * vx + vy * vy) + 1e-10f;
    float ux = vx / norm, uy = vy / norm;

    const float step = 1.0f / 9.0f;
    float sum = 0.f;
    #pragma unroll
    for (int m = 0; m < MID; m++) {
        float t = (float)m * step;
        int sx = (int)rintf(ax + vx * t);
        int sy = (int)rintf(ay + vy * t);
        const float* p = paf + ((size_t)sy * W + sx) * (2 * NLIMB) + 2 * l;
        sum += p[0] * ux + p[1] * uy;
    }
    float score = sum / (float)MID;
    score = score < 0.f ? 0.f : (score > 1.f ? 1.f : score);
    float res = (ma != 0.f && mb != 0.f) ? score : 0.f;
    out[OFF_CONN + l * (KTOP * KTOP) + i * KTOP + j] = res;
}

// ---------------------------------------------------------------------------
extern "C" void kernel_launch(void* const* d_in, const int* in_sizes, int n_in,
                              void* d_out, int out_size, void* d_ws, size_t ws_size,
                              hipStream_t stream)
{
    const float* hm  = (const float*)d_in[0];
    const float* paf = (const float*)d_in[1];
    float* out = (float*)d_out;

    const size_t planar_bytes = (size_t)NPART * HWSZ * sizeof(float);  // ~207.4 MB
    const size_t bl_bytes = (size_t)BLCAP * 4;                          // 4 MB
    const size_t head = 256;

    bool pathA = false;
    int cap = 1;
    if (ws_size > head + planar_bytes + bl_bytes + (size_t)NPART * 8 * 4096 + 512) {
        size_t avail = ws_size - head - planar_bytes - bl_bytes - 512;
        long long c = (long long)(avail / ((size_t)NPART * 8));
        cap = c > 65536 ? 65536 : (int)c;
        pathA = true;
    } else {
        size_t avail = ws_size > head ? ws_size - head : 0;
        long long c = (long long)(avail / ((size_t)NPART * 8));
        cap = c > 65536 ? 65536 : (int)c;
        if (cap < 1) cap = 1;
    }

    int*   counters = (int*)d_ws;
    float* cval = (float*)((char*)d_ws + head);
    int*   cidx = (int*)(cval + (size_t)NPART * cap);
    unsigned int* blg = (unsigned int*)(cidx + (size_t)NPART * cap);
    float* planar = (float*)(blg + (pathA ? (size_t)BLCAP : 0));
    planar = (float*)(((uintptr_t)planar + 255) & ~(uintptr_t)255);

    hipMemsetAsync(d_ws, 0, head, stream);

    if (pathA) {
        transpose_k<<<HWSZ / 256, 256, 0, stream>>>(hm, planar);
        dim3 gA(W / TW, (H + TH - 1) / TH, NPART);
        blur_peaks_v5<<<gA, 256, 0, stream>>>(planar, cval, cidx, counters, blg, cap);
        recheck_k<<<4096, 64, 0, stream>>>(planar, cval, cidx, counters, blg, cap);
    } else {
        dim3 gA(NPART, (W + TW - 1) / TW, (H + TH - 1) / TH);
        blur_peaks_gather<<<gA, 256, 0, stream>>>(hm, cval, cidx, counters, cap);
    }
    topk_kernel<<<NPART, BT, 0, stream>>>(cval, cidx, counters, cap, out);
    limbs_kernel<<<NLIMB, 1024, 0, stream>>>(out, paf, out);
}